// Round 4
// baseline (67.206 us; speedup 1.0000x reference)
//
#include <hip/hip_runtime.h>

// HQNN quanvolution, analytically collapsed (Heisenberg picture, DEPTH=1):
//   <Z0> = cos(w2)cos(w0)c0 - sin(w2)s0 s2
//   <Z1> = cos(w1)c1
//   <Z2> = cos(w0)c0 c2
//   <Z3> = cos(w3)<Z2>c3 - sin(w3)s3
// ck=cos(pi*pk), sk=sin(pi*pk); patch pixels p0=(i,j) p1=(i,j+1) p2=(i+1,j)
// p3=(i+1,j+1). Feature order for the linear head: f = q*729 + fi*27 + fj.
//
// R3: 4 images per block (grid 256, 1 block/CU). Each W float4 load feeds
// 40 FMAs -> W L2 traffic 60 -> 30 MB vs R2. sincospi staged in TWO passes
// (images 0-1 then 2-3) through a reused 12.5 KB sc/ss buffer so the 46.7 KB
// evl[4] fits beside it (59.2 KB static < 64 KB cap). part[] overlays evl
// after Phase 2 (evl dead there). All LDS writes merge to 16B-stride b128
// (conflict-free); reads are stride-1.

#define HD 28
#define NPIX 784          // 28*28
#define FD 27
#define NPATCH 729
#define NF 2916           // 4 * 729
#define NG 729            // float4 groups per W row
#define NOUT 10
#define PSTR 257          // padded stride for partials
#define IM 4              // images per block

__global__ __launch_bounds__(256)
void hqnn_fused(const float* __restrict__ x,
                const float* __restrict__ W,
                const float* __restrict__ bias,
                const float* __restrict__ wts,
                float* __restrict__ out)
{
    __shared__ float sc[2][NPIX];          // reused per image-pair pass
    __shared__ float ss[2][NPIX];
    __shared__ __align__(16) union V {
        float evl[IM][NF];                 // 46656 B
        float part[IM * NOUT][PSTR];       // 41120 B (overlay after Phase 2)
    } v;

    const int tid = threadIdx.x;

    // Circuit parameters (uniform; weights==0 at runtime -> cw=1, sw=0 exact).
    const float w0 = wts[0], w1 = wts[1], w2 = wts[2], w3 = wts[3];
    const float cw0 = cosf(w0);
    const float cw1 = cosf(w1);
    const float cw2 = cosf(w2), sw2 = sinf(w2);
    const float cw3 = cosf(w3), sw3 = sinf(w3);

    const float4* xb4 = (const float4*)(x + blockIdx.x * (IM * NPIX));

    // Phases 1 + 1.5, two image-pair passes.
#pragma unroll
    for (int pass = 0; pass < 2; ++pass) {
        // Phase 1: sincospi of 2 images into sc/ss (392 float4 pixel loads).
        for (int t = tid; t < 2 * NPIX / 4; t += 256) {
            const float4 vpx = xb4[pass * (2 * NPIX / 4) + t];
            const int gp   = t * 4;                   // 0..1567
            const int imgl = (gp >= NPIX) ? 1 : 0;
            const int off  = gp - imgl * NPIX;
            float s0, c0, s1, c1, s2, c2, s3, c3;
            sincospif(vpx.x, &s0, &c0);
            sincospif(vpx.y, &s1, &c1);
            sincospif(vpx.z, &s2, &c2);
            sincospif(vpx.w, &s3, &c3);
            sc[imgl][off]     = c0; ss[imgl][off]     = s0;
            sc[imgl][off + 1] = c1; ss[imgl][off + 1] = s1;
            sc[imgl][off + 2] = c2; ss[imgl][off + 2] = s2;
            sc[imgl][off + 3] = c3; ss[imgl][off + 3] = s3;
        }
        __syncthreads();

        // Phase 1.5: ev values for these 2 images, flat feature order.
        for (int pp = tid; pp < 2 * NPATCH; pp += 256) {
            const int imgl = pp / NPATCH;
            const int pa   = pp - imgl * NPATCH;
            const int fi   = pa / FD;
            const int fj   = pa - fi * FD;
            const int p    = fi * HD + fj;

            const float c00 = sc[imgl][p];
            const float c01 = sc[imgl][p + 1];
            const float c10 = sc[imgl][p + HD];
            const float c11 = sc[imgl][p + HD + 1];
            const float s00 = ss[imgl][p];
            const float s10 = ss[imgl][p + HD];
            const float s11 = ss[imgl][p + HD + 1];

            const int m = 2 * pass + imgl;
            const float ev2 = cw0 * c00 * c10;
            v.evl[m][pa]              = cw2 * cw0 * c00 - sw2 * s00 * s10;
            v.evl[m][NPATCH + pa]     = cw1 * c01;
            v.evl[m][2 * NPATCH + pa] = ev2;
            v.evl[m][3 * NPATCH + pa] = cw3 * ev2 * c11 - sw3 * s11;
        }
        __syncthreads();   // also protects sc/ss before the next pass's writes
    }

    // Phase 2: aligned float4 dots; 10 W loads feed 40 accumulators.
    float acc[IM][NOUT];
#pragma unroll
    for (int m = 0; m < IM; ++m)
#pragma unroll
        for (int o = 0; o < NOUT; ++o) acc[m][o] = 0.f;

    const float4* W4 = (const float4*)W;
    for (int g = tid; g < NG; g += 256) {
        float4 e[IM];
#pragma unroll
        for (int m = 0; m < IM; ++m) e[m] = ((const float4*)v.evl[m])[g];
#pragma unroll
        for (int o = 0; o < NOUT; ++o) {
            const float4 w = W4[o * NG + g];
#pragma unroll
            for (int m = 0; m < IM; ++m) {
                acc[m][o] += e[m].x * w.x + e[m].y * w.y
                           + e[m].z * w.z + e[m].w * w.w;
            }
        }
    }
    __syncthreads();   // evl reads done; part may overlay.

    // Phase 3: LDS partial reduction (part overlays evl).
#pragma unroll
    for (int m = 0; m < IM; ++m)
#pragma unroll
        for (int o = 0; o < NOUT; ++o) v.part[m * NOUT + o][tid] = acc[m][o];
    __syncthreads();

    if (tid < IM * NOUT * 4) {          // 160 lanes: 40 rows x 4 lanes
        const int row = tid >> 2;
        const int j   = tid & 3;
        float s = 0.f;
#pragma unroll
        for (int k = 0; k < 256; k += 4) s += v.part[row][j + k];
        s += __shfl_down(s, 2, 4);
        s += __shfl_down(s, 1, 4);
        if (j == 0) {
            const int img = row / NOUT;
            const int o   = row - img * NOUT;
            out[(blockIdx.x * IM + img) * NOUT + o] = s + bias[o];
        }
    }
}

extern "C" void kernel_launch(void* const* d_in, const int* in_sizes, int n_in,
                              void* d_out, int out_size, void* d_ws, size_t ws_size,
                              hipStream_t stream) {
    const float* x    = (const float*)d_in[0];   // (B,1,28,28) f32
    const float* W    = (const float*)d_in[1];   // (10, 2916) f32
    const float* bias = (const float*)d_in[2];   // (10,) f32
    const float* wts  = (const float*)d_in[3];   // (1,4) f32 (zeros)
    float* out = (float*)d_out;                  // (B,10) f32

    const int B = in_sizes[0] / NPIX;            // 1024
    hqnn_fused<<<B / IM, 256, 0, stream>>>(x, W, bias, wts, out);
}

// Round 5
// 65.439 us; speedup vs baseline: 1.0270x; 1.0270x over previous
//
#include <hip/hip_runtime.h>

// HQNN quanvolution, analytically collapsed (Heisenberg picture, DEPTH=1):
//   <Z0> = cos(w2)cos(w0)c0 - sin(w2)s0 s2
//   <Z1> = cos(w1)c1
//   <Z2> = cos(w0)c0 c2
//   <Z3> = cos(w3)<Z2>c3 - sin(w3)s3
// ck=cos(pi*pk), sk=sin(pi*pk); patch pixels p0=(i,j) p1=(i,j+1) p2=(i+1,j)
// p3=(i+1,j+1). Feature order for the linear head: f = q*729 + fi*27 + fj.
//
// R4 = revert to R2 (best measured: 65.13 us). IM=2 images/block, grid 512
// (2 blocks/CU, 12 waves/CU). R3's IM=4 (grid 256, 59 KB LDS, 2-pass
// staging) traded 0.85 us of W L2 traffic for ~3 us of exposed latency —
// occupancy/oversubscription wins at this scale. Kernel-side cost is
// ~3-5 us of the ~65 us total; the rest is harness-fixed (40 us ws-poison
// fill at 83% HBM peak + restores + graph gaps).

#define HD 28
#define NPIX 784          // 28*28
#define FD 27
#define NPATCH 729
#define NF 2916           // 4 * 729
#define NG 729            // float4 groups per W row
#define NOUT 10
#define PSTR 257          // padded stride for partials
#define IM 2              // images per block

__global__ __launch_bounds__(256)
void hqnn_fused(const float* __restrict__ x,
                const float* __restrict__ W,
                const float* __restrict__ bias,
                const float* __restrict__ wts,
                float* __restrict__ out)
{
    __shared__ __align__(16) float evl[IM][NF];
    __shared__ union U {
        struct { float sc[IM][NPIX]; float ss[IM][NPIX]; } tr;
        float part[IM * NOUT][PSTR];
    } u;

    const int tid = threadIdx.x;

    // Circuit parameters (uniform; weights==0 at runtime -> cw=1, sw=0 exact).
    const float w0 = wts[0], w1 = wts[1], w2 = wts[2], w3 = wts[3];
    const float cw0 = cosf(w0);
    const float cw1 = cosf(w1);
    const float cw2 = cosf(w2), sw2 = sinf(w2);
    const float cw3 = cosf(w3), sw3 = sinf(w3);

    // Phase 1: sincospi of both images into LDS (392 contiguous float4s).
    const float4* xb4 = (const float4*)(x + blockIdx.x * (IM * NPIX));
    for (int t = tid; t < IM * NPIX / 4; t += 256) {
        const float4 v = xb4[t];
        const int p4  = t * 4;
        const int img = (p4 >= NPIX) ? 1 : 0;   // IM == 2
        const int off = p4 - img * NPIX;
        float s0, c0, s1, c1, s2, c2, s3, c3;
        sincospif(v.x, &s0, &c0);
        sincospif(v.y, &s1, &c1);
        sincospif(v.z, &s2, &c2);
        sincospif(v.w, &s3, &c3);
        u.tr.sc[img][off]     = c0; u.tr.ss[img][off]     = s0;
        u.tr.sc[img][off + 1] = c1; u.tr.ss[img][off + 1] = s1;
        u.tr.sc[img][off + 2] = c2; u.tr.ss[img][off + 2] = s2;
        u.tr.sc[img][off + 3] = c3; u.tr.ss[img][off + 3] = s3;
    }
    __syncthreads();

    // Phase 1.5: ev values, flat in feature order f = q*729 + patch.
    for (int pp = tid; pp < IM * NPATCH; pp += 256) {
        const int img = pp / NPATCH;
        const int pa  = pp - img * NPATCH;
        const int fi  = pa / FD;
        const int fj  = pa - fi * FD;
        const int p   = fi * HD + fj;

        const float c00 = u.tr.sc[img][p];
        const float c01 = u.tr.sc[img][p + 1];
        const float c10 = u.tr.sc[img][p + HD];
        const float c11 = u.tr.sc[img][p + HD + 1];
        const float s00 = u.tr.ss[img][p];
        const float s10 = u.tr.ss[img][p + HD];
        const float s11 = u.tr.ss[img][p + HD + 1];

        const float ev2 = cw0 * c00 * c10;
        evl[img][pa]               = cw2 * cw0 * c00 - sw2 * s00 * s10;
        evl[img][NPATCH + pa]      = cw1 * c01;
        evl[img][2 * NPATCH + pa]  = ev2;
        evl[img][3 * NPATCH + pa]  = cw3 * ev2 * c11 - sw3 * s11;
    }
    __syncthreads();   // sc/ss dead from here; part may overlay them.

    // Phase 2: aligned float4 dots; 10 W loads feed 20 accumulators.
    float acc[IM][NOUT];
#pragma unroll
    for (int m = 0; m < IM; ++m)
#pragma unroll
        for (int o = 0; o < NOUT; ++o) acc[m][o] = 0.f;

    const float4* W4 = (const float4*)W;
    const float4* e0 = (const float4*)evl[0];
    const float4* e1 = (const float4*)evl[1];
    for (int g = tid; g < NG; g += 256) {
        const float4 a = e0[g];
        const float4 c = e1[g];
#pragma unroll
        for (int o = 0; o < NOUT; ++o) {
            const float4 w = W4[o * NG + g];
            acc[0][o] += a.x * w.x + a.y * w.y + a.z * w.z + a.w * w.w;
            acc[1][o] += c.x * w.x + c.y * w.y + c.z * w.z + c.w * w.w;
        }
    }

    // Phase 3: LDS partial reduction (part overlays sc/ss).
#pragma unroll
    for (int m = 0; m < IM; ++m)
#pragma unroll
        for (int o = 0; o < NOUT; ++o) u.part[m * NOUT + o][tid] = acc[m][o];
    __syncthreads();

    if (tid < IM * NOUT * 8) {          // 160 lanes: 20 rows x 8 lanes
        const int row = tid >> 3;
        const int j   = tid & 7;
        float s = 0.f;
#pragma unroll
        for (int k = 0; k < 256; k += 8) s += u.part[row][j + k];
        s += __shfl_down(s, 4, 8);
        s += __shfl_down(s, 2, 8);
        s += __shfl_down(s, 1, 8);
        if (j == 0) {
            const int img = (row >= NOUT) ? 1 : 0;
            const int o   = row - img * NOUT;
            out[(blockIdx.x * IM + img) * NOUT + o] = s + bias[o];
        }
    }
}

extern "C" void kernel_launch(void* const* d_in, const int* in_sizes, int n_in,
                              void* d_out, int out_size, void* d_ws, size_t ws_size,
                              hipStream_t stream) {
    const float* x    = (const float*)d_in[0];   // (B,1,28,28) f32
    const float* W    = (const float*)d_in[1];   // (10, 2916) f32
    const float* bias = (const float*)d_in[2];   // (10,) f32
    const float* wts  = (const float*)d_in[3];   // (1,4) f32 (zeros)
    float* out = (float*)d_out;                  // (B,10) f32

    const int B = in_sizes[0] / NPIX;            // 1024
    hqnn_fused<<<B / IM, 256, 0, stream>>>(x, W, bias, wts, out);
}